// Round 1
// 1061.999 us; speedup vs baseline: 1.0302x; 1.0302x over previous
//
#include <hip/hip_runtime.h>

#define B_SZ   8192
#define KOBJ   6
#define VD     2048
#define QD     1024
#define NHID_  1024
#define SEIN   128
#define M_TOT  (B_SZ * KOBJ)   // 49152
#define K_TOT  (VD + QD)       // 3072

typedef __bf16 bf16x8 __attribute__((ext_vector_type(8)));
typedef float  f32x4  __attribute__((ext_vector_type(4)));
typedef unsigned int uint4v __attribute__((ext_vector_type(4)));

__device__ __forceinline__ unsigned short f2bf(float f) {
    unsigned u = __builtin_bit_cast(unsigned, f);
    u += 0x7fffu + ((u >> 16) & 1u);   // RNE
    return (unsigned short)(u >> 16);
}

// -------------------------------------------------- fp32 -> bf16 (8 elem/thr)
__global__ __launch_bounds__(256) void conv_bf16(const float* __restrict__ src,
                                                 unsigned short* __restrict__ dst,
                                                 int n8) {
    int i = blockIdx.x * 256 + threadIdx.x;
    if (i < n8) {
        float4 f0 = ((const float4*)src)[2 * i];
        float4 f1 = ((const float4*)src)[2 * i + 1];
        uint4v d;
        d[0] = (unsigned)f2bf(f0.x) | ((unsigned)f2bf(f0.y) << 16);
        d[1] = (unsigned)f2bf(f0.z) | ((unsigned)f2bf(f0.w) << 16);
        d[2] = (unsigned)f2bf(f1.x) | ((unsigned)f2bf(f1.y) << 16);
        d[3] = (unsigned)f2bf(f1.z) | ((unsigned)f2bf(f1.w) << 16);
        ((uint4v*)dst)[i] = d;
    }
}

// --------------------------------------------- Gq[b][n] = q[b].W1q[n] + b1[n]
// Same m97-style structure as the main GEMM (128x128 tile, BK=32,
// global_load_lds w16, XOR chunk swizzle pre-applied on the GLOBAL address).
// A = qb [8192 x 1024], B = W1b rows, k-offset +VD (the q-columns of W1).
__global__ __launch_bounds__(256) void gemm_q(
    const unsigned short* __restrict__ qb, const unsigned short* __restrict__ W1b,
    const float* __restrict__ b1, float* __restrict__ Gq)
{
    __shared__ unsigned short At[128 * 32];
    __shared__ unsigned short Bt[128 * 32];

    const int tid  = threadIdx.x;
    const int bid  = blockIdx.x;
    const int nb   = bid & 7;
    const int mb   = bid >> 3;
    const int m0   = mb * 128;
    const int n0   = nb * 128;
    const int wave = tid >> 6, lane = tid & 63;
    const int quad = lane >> 4, l16 = lane & 15;
    const int wr   = (wave >> 1) * 64, wc = (wave & 1) * 64;

    const unsigned short* ga[2];
    const unsigned short* gb[2];
    unsigned short* ldsA[2];
    unsigned short* ldsB[2];
    #pragma unroll
    for (int c = 0; c < 2; ++c) {
        int seg = wave * 2 + c;
        int row = seg * 16 + (lane >> 2);
        int ch  = (lane & 3) ^ ((row >> 1) & 3);
        ga[c]   = qb + (size_t)(m0 + row) * QD + ch * 8;
        gb[c]   = W1b + (size_t)(n0 + row) * K_TOT + VD + ch * 8;
        ldsA[c] = &At[seg * 512];
        ldsB[c] = &Bt[seg * 512];
    }

    f32x4 acc[4][4] = {};
    const int swz = (l16 >> 1) & 3;

    for (int kk = 0; kk < QD; kk += 32) {
        __syncthreads();
        #pragma unroll
        for (int c = 0; c < 2; ++c)
            __builtin_amdgcn_global_load_lds(
                (const __attribute__((address_space(1))) void*)(ga[c] + kk),
                (__attribute__((address_space(3))) void*)ldsA[c], 16, 0, 0);
        #pragma unroll
        for (int c = 0; c < 2; ++c)
            __builtin_amdgcn_global_load_lds(
                (const __attribute__((address_space(1))) void*)(gb[c] + kk),
                (__attribute__((address_space(3))) void*)ldsB[c], 16, 0, 0);
        __syncthreads();

        bf16x8 af[4], bfr[4];
        #pragma unroll
        for (int i = 0; i < 4; ++i)
            af[i] = __builtin_bit_cast(bf16x8,
                *(const uint4v*)&At[(wr + i * 16 + l16) * 32 + ((quad ^ swz) * 8)]);
        #pragma unroll
        for (int j = 0; j < 4; ++j)
            bfr[j] = __builtin_bit_cast(bf16x8,
                *(const uint4v*)&Bt[(wc + j * 16 + l16) * 32 + ((quad ^ swz) * 8)]);
        #pragma unroll
        for (int i = 0; i < 4; ++i)
            #pragma unroll
            for (int j = 0; j < 4; ++j)
                acc[i][j] = __builtin_amdgcn_mfma_f32_16x16x32_bf16(af[i], bfr[j], acc[i][j], 0, 0, 0);
    }

    #pragma unroll
    for (int i = 0; i < 4; ++i)
        #pragma unroll
        for (int j = 0; j < 4; ++j) {
            int n = n0 + wc + j * 16 + l16;
            float bv = b1[n];
            #pragma unroll
            for (int r = 0; r < 4; ++r) {
                int m = m0 + wr + i * 16 + quad * 4 + r;
                Gq[(size_t)m * NHID_ + n] = acc[i][j][r] + bv;
            }
        }
}

// ------------------------------------------------- fused GEMM + ReLU + Wl-dot
// K reduced to VD=2048: the q.W1q part comes in via Gq (per-batch, 6x reuse).
__global__ __launch_bounds__(256) void gemm_logits(
    const unsigned short* __restrict__ vb, const unsigned short* __restrict__ W1b,
    const float* __restrict__ Gq, const float* __restrict__ Wl,
    float* __restrict__ logits)
{
    __shared__ unsigned short At[128 * 32];
    __shared__ unsigned short Bt[128 * 32];

    const int tid  = threadIdx.x;
    const int bid  = blockIdx.x;
    const int nb   = bid & 7;        // n fastest -> 8 N-blocks share A rows in L3
    const int mb   = bid >> 3;
    const int m0   = mb * 128;
    const int n0   = nb * 128;
    const int wave = tid >> 6, lane = tid & 63;
    const int quad = lane >> 4, l16 = lane & 15;
    const int wr   = (wave >> 1) * 64, wc = (wave & 1) * 64;

    const unsigned short* gav[2];
    const unsigned short* gb[2];
    unsigned short* ldsA[2];
    unsigned short* ldsB[2];
    #pragma unroll
    for (int c = 0; c < 2; ++c) {
        int seg = wave * 2 + c;
        int row = seg * 16 + (lane >> 2);
        int ch  = (lane & 3) ^ ((row >> 1) & 3);
        gav[c]  = vb + (size_t)(m0 + row) * VD + ch * 8;
        gb[c]   = W1b + (size_t)(n0 + row) * K_TOT + ch * 8;
        ldsA[c] = &At[seg * 512];
        ldsB[c] = &Bt[seg * 512];
    }

    f32x4 acc[4][4] = {};
    const int swz = (l16 >> 1) & 3;

    for (int kk = 0; kk < VD; kk += 32) {
        __syncthreads();
        #pragma unroll
        for (int c = 0; c < 2; ++c)
            __builtin_amdgcn_global_load_lds(
                (const __attribute__((address_space(1))) void*)(gav[c] + kk),
                (__attribute__((address_space(3))) void*)ldsA[c], 16, 0, 0);
        #pragma unroll
        for (int c = 0; c < 2; ++c)
            __builtin_amdgcn_global_load_lds(
                (const __attribute__((address_space(1))) void*)(gb[c] + kk),
                (__attribute__((address_space(3))) void*)ldsB[c], 16, 0, 0);
        __syncthreads();   // compiler inserts s_waitcnt vmcnt(0) before barrier

        bf16x8 af[4], bfr[4];
        #pragma unroll
        for (int i = 0; i < 4; ++i)
            af[i] = __builtin_bit_cast(bf16x8,
                *(const uint4v*)&At[(wr + i * 16 + l16) * 32 + ((quad ^ swz) * 8)]);
        #pragma unroll
        for (int j = 0; j < 4; ++j)
            bfr[j] = __builtin_bit_cast(bf16x8,
                *(const uint4v*)&Bt[(wc + j * 16 + l16) * 32 + ((quad ^ swz) * 8)]);
        #pragma unroll
        for (int i = 0; i < 4; ++i)
            #pragma unroll
            for (int j = 0; j < 4; ++j)
                acc[i][j] = __builtin_amdgcn_mfma_f32_16x16x32_bf16(af[i], bfr[j], acc[i][j], 0, 0, 0);
    }

    // epilogue: +Gq[m/6] (has b1 folded in), relu, dot with Wl over 128 cols
    #pragma unroll
    for (int i = 0; i < 4; ++i) {
        #pragma unroll
        for (int r = 0; r < 4; ++r) {
            int m = m0 + wr + i * 16 + quad * 4 + r;
            const float* gqr = Gq + (size_t)(m / KOBJ) * NHID_;
            float sum = 0.f;
            #pragma unroll
            for (int j = 0; j < 4; ++j) {
                int n = n0 + wc + j * 16 + l16;
                float h = fmaxf(acc[i][j][r] + gqr[n], 0.f);
                sum = fmaf(h, Wl[n], sum);
            }
            sum += __shfl_xor(sum, 1);
            sum += __shfl_xor(sum, 2);
            sum += __shfl_xor(sum, 4);
            sum += __shfl_xor(sum, 8);
            if (l16 == 0) atomicAdd(&logits[m], sum);
        }
    }
}

// ---------------------------------------- per-b: softmax + mask + SE gate + s
__global__ __launch_bounds__(256) void se_kernel(
    const float* __restrict__ logits, const float* __restrict__ mask,
    const float* __restrict__ bl,
    const float* __restrict__ Wse1, const float* __restrict__ Wse2,
    float* __restrict__ out_att, float* __restrict__ s_buf)
{
    int b = blockIdx.x * 256 + threadIdx.x;
    if (b >= B_SZ) return;
    float w[KOBJ];
    float blv = bl[0];
    #pragma unroll
    for (int k = 0; k < KOBJ; ++k) w[k] = logits[b * KOBJ + k] + blv;

    float mx = w[0];
    #pragma unroll
    for (int k = 1; k < KOBJ; ++k) mx = fmaxf(mx, w[k]);
    float e[KOBJ], den = 0.f;
    #pragma unroll
    for (int k = 0; k < KOBJ; ++k) { e[k] = __expf(w[k] - mx); den += e[k]; }
    float rden = 1.f / den;
    #pragma unroll
    for (int k = 0; k < KOBJ; ++k) out_att[b * KOBJ + k] = e[k] * rden;

    float wcm[KOBJ], tot = 0.f;
    #pragma unroll
    for (int k = 0; k < KOBJ; ++k) { wcm[k] = w[k] * mask[b * KOBJ + k]; tot += wcm[k]; }

    #pragma unroll
    for (int k = 0; k < KOBJ; ++k) {
        float x = tot - wcm[k];
        float a = 0.f;
        for (int i = 0; i < SEIN; ++i)
            a = fmaf(fmaxf(x * Wse1[i], 0.f), Wse2[i], a);
        float y = 1.f / (1.f + __expf(-a));
        s_buf[b * KOBJ + k] = x * (1.f - y) + w[k];
    }
}

// ------------------------------------------- out2[m,d] = s[m]*Wf[d] + bf[d]
__global__ __launch_bounds__(256) void out_writer(
    const float* __restrict__ s_buf, const float* __restrict__ Wf,
    const float* __restrict__ bfv, float* __restrict__ out)
{
    int m = blockIdx.x;
    float s = s_buf[m];
    const float4* wf4 = (const float4*)Wf;
    const float4* bf4 = (const float4*)bfv;
    float4* o4 = (float4*)(out + (size_t)m * VD);
    #pragma unroll
    for (int it = 0; it < VD / 4 / 256; ++it) {
        int t = threadIdx.x + it * 256;
        float4 wv = wf4[t], bv = bf4[t];
        float4 r;
        r.x = fmaf(s, wv.x, bv.x);
        r.y = fmaf(s, wv.y, bv.y);
        r.z = fmaf(s, wv.z, bv.z);
        r.w = fmaf(s, wv.w, bv.w);
        o4[t] = r;
    }
}

extern "C" void kernel_launch(void* const* d_in, const int* in_sizes, int n_in,
                              void* d_out, int out_size, void* d_ws, size_t ws_size,
                              hipStream_t stream) {
    const float* v    = (const float*)d_in[0];
    const float* q    = (const float*)d_in[1];
    const float* mask = (const float*)d_in[2];
    const float* W1   = (const float*)d_in[3];
    const float* b1   = (const float*)d_in[4];
    const float* Wl   = (const float*)d_in[5];
    const float* bl   = (const float*)d_in[6];
    const float* Wse1 = (const float*)d_in[7];
    const float* Wse2 = (const float*)d_in[8];
    const float* Wf   = (const float*)d_in[9];
    const float* bfv  = (const float*)d_in[10];
    float* out = (float*)d_out;

    // ws: W1b bf16 (6 MB) + logits + s_buf  (~6.7 MB, known to fit)
    char* ws = (char*)d_ws;
    unsigned short* W1b = (unsigned short*)ws;                       // 6291456 B
    float* logits = (float*)(ws + 6291456);                          // 196608 B
    float* s_buf  = (float*)(ws + 6291456 + 196608);                 // 196608 B

    // Scratch in the TAIL of d_out (out2 region, 402 MB):
    // vb (192 MB) + qb (16 MB) + Gq (32 MB), all dead before out_writer.
    unsigned short* vb = (unsigned short*)((char*)d_out + (size_t)M_TOT * 4);
    unsigned short* qb = (unsigned short*)((char*)d_out + (size_t)M_TOT * 4 + 201326592);
    float* Gq = (float*)((char*)d_out + (size_t)M_TOT * 4 + 201326592 + 16777216);

    hipMemsetAsync(logits, 0, M_TOT * sizeof(float), stream);
    conv_bf16<<<(NHID_ * K_TOT / 8 + 255) / 256, 256, 0, stream>>>(W1, W1b, NHID_ * K_TOT / 8);
    conv_bf16<<<(B_SZ * QD / 8 + 255) / 256, 256, 0, stream>>>(q, qb, B_SZ * QD / 8);
    gemm_q<<<(B_SZ / 128) * (NHID_ / 128), 256, 0, stream>>>(qb, W1b, b1, Gq);
    conv_bf16<<<(M_TOT * VD / 8 + 255) / 256, 256, 0, stream>>>(v, vb, M_TOT * VD / 8);
    gemm_logits<<<(M_TOT / 128) * (NHID_ / 128), 256, 0, stream>>>(vb, W1b, Gq, Wl, logits);
    se_kernel<<<(B_SZ + 255) / 256, 256, 0, stream>>>(logits, mask, bl, Wse1, Wse2, out, s_buf);
    out_writer<<<M_TOT, 256, 0, stream>>>(s_buf, Wf, bfv, out + M_TOT);
}

// Round 2
// 1038.121 us; speedup vs baseline: 1.0539x; 1.0230x over previous
//
#include <hip/hip_runtime.h>

#define B_SZ   8192
#define KOBJ   6
#define VD     2048
#define QD     1024
#define NHID_  1024
#define SEIN   128
#define M_TOT  (B_SZ * KOBJ)   // 49152
#define K_TOT  (VD + QD)       // 3072

typedef __bf16 bf16x8 __attribute__((ext_vector_type(8)));
typedef float  f32x4  __attribute__((ext_vector_type(4)));
typedef float  f32x8  __attribute__((ext_vector_type(8)));
typedef unsigned int uint4v __attribute__((ext_vector_type(4)));

__device__ __forceinline__ unsigned short f2bf(float f) {
    unsigned u = __builtin_bit_cast(unsigned, f);
    u += 0x7fffu + ((u >> 16) & 1u);   // RNE
    return (unsigned short)(u >> 16);
}

// -------------------------------------------------- fp32 -> bf16 (8 elem/thr)
__global__ __launch_bounds__(256) void conv_bf16(const float* __restrict__ src,
                                                 unsigned short* __restrict__ dst,
                                                 int n8) {
    int i = blockIdx.x * 256 + threadIdx.x;
    if (i < n8) {
        float4 f0 = ((const float4*)src)[2 * i];
        float4 f1 = ((const float4*)src)[2 * i + 1];
        uint4v d;
        d[0] = (unsigned)f2bf(f0.x) | ((unsigned)f2bf(f0.y) << 16);
        d[1] = (unsigned)f2bf(f0.z) | ((unsigned)f2bf(f0.w) << 16);
        d[2] = (unsigned)f2bf(f1.x) | ((unsigned)f2bf(f1.y) << 16);
        d[3] = (unsigned)f2bf(f1.z) | ((unsigned)f2bf(f1.w) << 16);
        ((uint4v*)dst)[i] = d;
    }
}

// --------------------------------------------- Gq[b][n] = q[b].W1q[n] + b1[n]
__global__ __launch_bounds__(256) void gemm_q(
    const unsigned short* __restrict__ qb, const unsigned short* __restrict__ W1b,
    const float* __restrict__ b1, float* __restrict__ Gq)
{
    __shared__ unsigned short At[128 * 32];
    __shared__ unsigned short Bt[128 * 32];

    const int tid  = threadIdx.x;
    const int bid  = blockIdx.x;
    const int nb   = bid & 7;
    const int mb   = bid >> 3;
    const int m0   = mb * 128;
    const int n0   = nb * 128;
    const int wave = tid >> 6, lane = tid & 63;
    const int quad = lane >> 4, l16 = lane & 15;
    const int wr   = (wave >> 1) * 64, wc = (wave & 1) * 64;

    const unsigned short* ga[2];
    const unsigned short* gb[2];
    unsigned short* ldsA[2];
    unsigned short* ldsB[2];
    #pragma unroll
    for (int c = 0; c < 2; ++c) {
        int seg = wave * 2 + c;
        int row = seg * 16 + (lane >> 2);
        int ch  = (lane & 3) ^ ((row >> 1) & 3);
        ga[c]   = qb + (size_t)(m0 + row) * QD + ch * 8;
        gb[c]   = W1b + (size_t)(n0 + row) * K_TOT + VD + ch * 8;
        ldsA[c] = &At[seg * 512];
        ldsB[c] = &Bt[seg * 512];
    }

    f32x4 acc[4][4] = {};
    const int swz = (l16 >> 1) & 3;

    for (int kk = 0; kk < QD; kk += 32) {
        __syncthreads();
        #pragma unroll
        for (int c = 0; c < 2; ++c)
            __builtin_amdgcn_global_load_lds(
                (const __attribute__((address_space(1))) void*)(ga[c] + kk),
                (__attribute__((address_space(3))) void*)ldsA[c], 16, 0, 0);
        #pragma unroll
        for (int c = 0; c < 2; ++c)
            __builtin_amdgcn_global_load_lds(
                (const __attribute__((address_space(1))) void*)(gb[c] + kk),
                (__attribute__((address_space(3))) void*)ldsB[c], 16, 0, 0);
        __syncthreads();

        bf16x8 af[4], bfr[4];
        #pragma unroll
        for (int i = 0; i < 4; ++i)
            af[i] = __builtin_bit_cast(bf16x8,
                *(const uint4v*)&At[(wr + i * 16 + l16) * 32 + ((quad ^ swz) * 8)]);
        #pragma unroll
        for (int j = 0; j < 4; ++j)
            bfr[j] = __builtin_bit_cast(bf16x8,
                *(const uint4v*)&Bt[(wc + j * 16 + l16) * 32 + ((quad ^ swz) * 8)]);
        #pragma unroll
        for (int i = 0; i < 4; ++i)
            #pragma unroll
            for (int j = 0; j < 4; ++j)
                acc[i][j] = __builtin_amdgcn_mfma_f32_16x16x32_bf16(af[i], bfr[j], acc[i][j], 0, 0, 0);
    }

    #pragma unroll
    for (int i = 0; i < 4; ++i)
        #pragma unroll
        for (int j = 0; j < 4; ++j) {
            int n = n0 + wc + j * 16 + l16;
            float bv = b1[n];
            #pragma unroll
            for (int r = 0; r < 4; ++r) {
                int m = m0 + wr + i * 16 + quad * 4 + r;
                Gq[(size_t)m * NHID_ + n] = acc[i][j][r] + bv;
            }
        }
}

// ------------------------------------------------- fused GEMM + ReLU + Wl-dot
// A = v read DIRECTLY as fp32 (no conv pass, no vb scratch): reg-staged
// global fp32 -> convertvector bf16 -> ds_write_b128 to the SAME swizzled
// LDS address gload_lds used to fill -> read/MFMA path is bit-identical.
// T1: tile-group->XCD pinning so the 8 nb-blocks of one mb share one L2.
__global__ __launch_bounds__(256) void gemm_logits(
    const float* __restrict__ v, const unsigned short* __restrict__ W1b,
    const float* __restrict__ Gq, const float* __restrict__ Wl,
    float* __restrict__ logits)
{
    __shared__ unsigned short At[128 * 32];
    __shared__ unsigned short Bt[128 * 32];

    const int tid  = threadIdx.x;
    const int bid  = blockIdx.x;
    // dispatch order round-robins XCD = bid & 7; give each XCD a contiguous
    // mb range and enumerate (mb_local, nb) within it -> the 8 N-blocks of a
    // given mb are consecutive on ONE XCD and share its L2 A-tile.
    const int xcd = bid & 7;
    const int j   = bid >> 3;                 // 0..383 within this XCD
    const int nb  = j & 7;
    const int mb  = xcd * 48 + (j >> 3);      // 384/8 = 48 mb per XCD
    const int m0  = mb * 128;
    const int n0  = nb * 128;
    const int wave = tid >> 6, lane = tid & 63;
    const int quad = lane >> 4, l16 = lane & 15;
    const int wr   = (wave >> 1) * 64, wc = (wave & 1) * 64;

    // A reg-staging geometry: seg = wave*2+c covers rows seg*16..+15;
    // this lane owns row = seg*16 + (lane>>2), LDS 16B-pos (lane&3),
    // which must hold global data chunk (lane&3) ^ ((row>>1)&3).
    const float* gav[2];
    unsigned short* ldsAw[2];
    const unsigned short* gb[2];
    unsigned short* ldsB[2];
    #pragma unroll
    for (int c = 0; c < 2; ++c) {
        int seg = wave * 2 + c;
        int row = seg * 16 + (lane >> 2);
        int ch  = (lane & 3) ^ ((row >> 1) & 3);
        gav[c]  = v + (size_t)(m0 + row) * VD + ch * 8;
        ldsAw[c] = &At[seg * 512 + lane * 8];     // linear slot (== gload_lds dest)
        gb[c]   = W1b + (size_t)(n0 + row) * K_TOT + ch * 8;
        ldsB[c] = &Bt[seg * 512];
    }

    f32x4 acc[4][4] = {};
    const int swz = (l16 >> 1) & 3;

    for (int kk = 0; kk < VD; kk += 32) {
        __syncthreads();
        // B: async DMA to LDS (bf16, pre-swizzled source)
        #pragma unroll
        for (int c = 0; c < 2; ++c)
            __builtin_amdgcn_global_load_lds(
                (const __attribute__((address_space(1))) void*)(gb[c] + kk),
                (__attribute__((address_space(3))) void*)ldsB[c], 16, 0, 0);
        // A: fp32 -> regs -> bf16 -> LDS (same swizzled image as before)
        float4 a0[2], a1[2];
        #pragma unroll
        for (int c = 0; c < 2; ++c) {
            const float4* p = (const float4*)(gav[c] + kk);
            a0[c] = p[0];
            a1[c] = p[1];
        }
        #pragma unroll
        for (int c = 0; c < 2; ++c) {
            f32x8 f;
            f[0] = a0[c].x; f[1] = a0[c].y; f[2] = a0[c].z; f[3] = a0[c].w;
            f[4] = a1[c].x; f[5] = a1[c].y; f[6] = a1[c].z; f[7] = a1[c].w;
            bf16x8 w = __builtin_convertvector(f, bf16x8);   // RNE
            *(uint4v*)ldsAw[c] = __builtin_bit_cast(uint4v, w);
        }
        __syncthreads();   // drains vmcnt (B DMA) + lgkmcnt (A ds_write)

        bf16x8 af[4], bfr[4];
        #pragma unroll
        for (int i = 0; i < 4; ++i)
            af[i] = __builtin_bit_cast(bf16x8,
                *(const uint4v*)&At[(wr + i * 16 + l16) * 32 + ((quad ^ swz) * 8)]);
        #pragma unroll
        for (int j2 = 0; j2 < 4; ++j2)
            bfr[j2] = __builtin_bit_cast(bf16x8,
                *(const uint4v*)&Bt[(wc + j2 * 16 + l16) * 32 + ((quad ^ swz) * 8)]);
        #pragma unroll
        for (int i = 0; i < 4; ++i)
            #pragma unroll
            for (int j2 = 0; j2 < 4; ++j2)
                acc[i][j2] = __builtin_amdgcn_mfma_f32_16x16x32_bf16(af[i], bfr[j2], acc[i][j2], 0, 0, 0);
    }

    // epilogue: +Gq[m/6] (has b1 folded in), relu, dot with Wl over 128 cols
    #pragma unroll
    for (int i = 0; i < 4; ++i) {
        #pragma unroll
        for (int r = 0; r < 4; ++r) {
            int m = m0 + wr + i * 16 + quad * 4 + r;
            const float* gqr = Gq + (size_t)(m / KOBJ) * NHID_;
            float sum = 0.f;
            #pragma unroll
            for (int j2 = 0; j2 < 4; ++j2) {
                int n = n0 + wc + j2 * 16 + l16;
                float h = fmaxf(acc[i][j2][r] + gqr[n], 0.f);
                sum = fmaf(h, Wl[n], sum);
            }
            sum += __shfl_xor(sum, 1);
            sum += __shfl_xor(sum, 2);
            sum += __shfl_xor(sum, 4);
            sum += __shfl_xor(sum, 8);
            if (l16 == 0) atomicAdd(&logits[m], sum);
        }
    }
}

// ---------------------------------------- per-b: softmax + mask + SE gate + s
__global__ __launch_bounds__(256) void se_kernel(
    const float* __restrict__ logits, const float* __restrict__ mask,
    const float* __restrict__ bl,
    const float* __restrict__ Wse1, const float* __restrict__ Wse2,
    float* __restrict__ out_att, float* __restrict__ s_buf)
{
    int b = blockIdx.x * 256 + threadIdx.x;
    if (b >= B_SZ) return;
    float w[KOBJ];
    float blv = bl[0];
    #pragma unroll
    for (int k = 0; k < KOBJ; ++k) w[k] = logits[b * KOBJ + k] + blv;

    float mx = w[0];
    #pragma unroll
    for (int k = 1; k < KOBJ; ++k) mx = fmaxf(mx, w[k]);
    float e[KOBJ], den = 0.f;
    #pragma unroll
    for (int k = 0; k < KOBJ; ++k) { e[k] = __expf(w[k] - mx); den += e[k]; }
    float rden = 1.f / den;
    #pragma unroll
    for (int k = 0; k < KOBJ; ++k) out_att[b * KOBJ + k] = e[k] * rden;

    float wcm[KOBJ], tot = 0.f;
    #pragma unroll
    for (int k = 0; k < KOBJ; ++k) { wcm[k] = w[k] * mask[b * KOBJ + k]; tot += wcm[k]; }

    #pragma unroll
    for (int k = 0; k < KOBJ; ++k) {
        float x = tot - wcm[k];
        float a = 0.f;
        for (int i = 0; i < SEIN; ++i)
            a = fmaf(fmaxf(x * Wse1[i], 0.f), Wse2[i], a);
        float y = 1.f / (1.f + __expf(-a));
        s_buf[b * KOBJ + k] = x * (1.f - y) + w[k];
    }
}

// ------------------------------------------- out2[m,d] = s[m]*Wf[d] + bf[d]
__global__ __launch_bounds__(256) void out_writer(
    const float* __restrict__ s_buf, const float* __restrict__ Wf,
    const float* __restrict__ bfv, float* __restrict__ out)
{
    int m = blockIdx.x;
    float s = s_buf[m];
    const float4* wf4 = (const float4*)Wf;
    const float4* bf4 = (const float4*)bfv;
    float4* o4 = (float4*)(out + (size_t)m * VD);
    #pragma unroll
    for (int it = 0; it < VD / 4 / 256; ++it) {
        int t = threadIdx.x + it * 256;
        float4 wv = wf4[t], bv = bf4[t];
        float4 r;
        r.x = fmaf(s, wv.x, bv.x);
        r.y = fmaf(s, wv.y, bv.y);
        r.z = fmaf(s, wv.z, bv.z);
        r.w = fmaf(s, wv.w, bv.w);
        o4[t] = r;
    }
}

extern "C" void kernel_launch(void* const* d_in, const int* in_sizes, int n_in,
                              void* d_out, int out_size, void* d_ws, size_t ws_size,
                              hipStream_t stream) {
    const float* v    = (const float*)d_in[0];
    const float* q    = (const float*)d_in[1];
    const float* mask = (const float*)d_in[2];
    const float* W1   = (const float*)d_in[3];
    const float* b1   = (const float*)d_in[4];
    const float* Wl   = (const float*)d_in[5];
    const float* bl   = (const float*)d_in[6];
    const float* Wse1 = (const float*)d_in[7];
    const float* Wse2 = (const float*)d_in[8];
    const float* Wf   = (const float*)d_in[9];
    const float* bfv  = (const float*)d_in[10];
    float* out = (float*)d_out;

    // ws: W1b bf16 (6 MB) + logits + s_buf  (~6.7 MB, known to fit)
    char* ws = (char*)d_ws;
    unsigned short* W1b = (unsigned short*)ws;                       // 6291456 B
    float* logits = (float*)(ws + 6291456);                          // 196608 B
    float* s_buf  = (float*)(ws + 6291456 + 196608);                 // 196608 B

    // Scratch in the TAIL of d_out (out2 region, 402 MB):
    // qb (16 MB) + Gq (32 MB), both dead before out_writer overwrites.
    unsigned short* qb = (unsigned short*)((char*)d_out + (size_t)M_TOT * 4 + 201326592);
    float* Gq = (float*)((char*)d_out + (size_t)M_TOT * 4 + 201326592 + 16777216);

    hipMemsetAsync(logits, 0, M_TOT * sizeof(float), stream);
    conv_bf16<<<(NHID_ * K_TOT / 8 + 255) / 256, 256, 0, stream>>>(W1, W1b, NHID_ * K_TOT / 8);
    conv_bf16<<<(B_SZ * QD / 8 + 255) / 256, 256, 0, stream>>>(q, qb, B_SZ * QD / 8);
    gemm_q<<<(B_SZ / 128) * (NHID_ / 128), 256, 0, stream>>>(qb, W1b, b1, Gq);
    gemm_logits<<<(M_TOT / 128) * (NHID_ / 128), 256, 0, stream>>>(v, W1b, Gq, Wl, logits);
    se_kernel<<<(B_SZ + 255) / 256, 256, 0, stream>>>(logits, mask, bl, Wse1, Wse2, out, s_buf);
    out_writer<<<M_TOT, 256, 0, stream>>>(s_buf, Wf, bfv, out + M_TOT);
}